// Round 2
// baseline (2156.956 us; speedup 1.0000x reference)
//
#include <hip/hip_runtime.h>
#include <cstdint>

// Problem constants (fixed by reference setup_inputs)
#define B_IMG   8
#define N_PROP  16384
#define NCAND   16384        // per-(image,label) candidate array stride
#define NMS_MAX 640
#define DETS    320
#define SCORE_TH 0.3f
#define NMS_TH   0.3f
#define MIN_SZ   0.01f
#define BBOX_CLIP_F 4.135166556742356f   // log(1000/16), same f32 as reference

#define NMS_THREADS 512
#define NW          (NMS_THREADS/64)     // 8 waves
#define RSLOTS      24                   // register slots per thread -> 12288 capacity
#define REGCAP      (NMS_THREADS*RSLOTS)

// -------- Phase A: decode + softmax + validity -> compacted per-(b,label) lists --------
__global__ __launch_bounds__(256) void decode_compact(
    const float* __restrict__ logits, const float* __restrict__ rel,
    const float* __restrict__ props, const int* __restrict__ img_size,
    int* __restrict__ cnt, float* __restrict__ sc_ws, int* __restrict__ n_ws,
    float4* __restrict__ ob_ws, float4* __restrict__ rb_ws)
{
    int t = blockIdx.x * 256 + threadIdx.x;     // t in [0, B*N)
    int b = t >> 14;
    int n = t & (N_PROP - 1);
    float fs = (float)img_size[0];

    float l0 = logits[3*t+0], l1 = logits[3*t+1], l2 = logits[3*t+2];
    float m  = fmaxf(l0, fmaxf(l1, l2));
    float e0 = expf(l0 - m), e1 = expf(l1 - m), e2 = expf(l2 - m);
    float sum = e0 + e1 + e2;
    float p[2] = { e1 / sum, e2 / sum };

    float4 pr = reinterpret_cast<const float4*>(props)[t];
    float w  = pr.z - pr.x, h  = pr.w - pr.y;
    float cx = pr.x + 0.5f*w, cy = pr.y + 0.5f*h;

    const float4* relv = reinterpret_cast<const float4*>(rel) + 3*t;
    int lane = threadIdx.x & 63;
    unsigned long long lanemask = (1ull << lane) - 1ull;

    #pragma unroll
    for (int c = 1; c <= 2; ++c) {
        float4 r = relv[c];
        float dx = r.x / 10.0f, dy = r.y / 10.0f;
        float dw = fminf(r.z / 5.0f, BBOX_CLIP_F);
        float dh = fminf(r.w / 5.0f, BBOX_CLIP_F);
        float pcx = dx * w + cx, pcy = dy * h + cy;
        float pw  = expf(dw) * w, ph  = expf(dh) * h;
        float x1 = pcx - 0.5f*pw, y1 = pcy - 0.5f*ph;
        float x2 = pcx + 0.5f*pw, y2 = pcy + 0.5f*ph;
        x1 = fminf(fmaxf(x1, 0.f), fs); y1 = fminf(fmaxf(y1, 0.f), fs);
        x2 = fminf(fmaxf(x2, 0.f), fs); y2 = fminf(fmaxf(y2, 0.f), fs);
        float sc = p[c-1];
        bool valid = (sc > SCORE_TH) && (x2 - x1 >= MIN_SZ) && (y2 - y1 >= MIN_SZ);

        unsigned long long mball = __ballot(valid);
        int g   = b*2 + (c-1);
        int tot = __popcll(mball);
        int base = 0;
        if (lane == 0 && tot > 0) base = atomicAdd(&cnt[g], tot);
        base = __shfl(base, 0);
        if (valid) {
            int slot = g*NCAND + base + __popcll(mball & lanemask);
            sc_ws[slot] = sc;
            n_ws[slot]  = n;                     // original proposal index (flat idx j = 2n+c-1)
            float off = (float)c * (fs + 1.0f);  // matches reference nboxes bit-for-bit
            ob_ws[slot] = make_float4(x1+off, y1+off, x2+off, y2+off);
            rb_ws[slot] = make_float4(x1, y1, x2, y2);
        }
    }
}

// -------- Phase B: per-(image,label) greedy NMS, register-resident candidates --------
__global__ __launch_bounds__(NMS_THREADS, 2) void nms_greedy(
    float* __restrict__ sc_ws, const int* __restrict__ n_ws,
    const float4* __restrict__ ob_ws, const float4* __restrict__ rb_ws,
    const int* __restrict__ cnt, int* __restrict__ Kout,
    float* __restrict__ survS, int* __restrict__ survN, float4* __restrict__ survB)
{
    __shared__ unsigned long long warpKey[2][NW];   // parity double-buffer (race-free 1-barrier loop)
    __shared__ int                warpSlot[2][NW];
    __shared__ float sS[NMS_MAX];                   // survivors staged in LDS, flushed after loop
    __shared__ int   sN[NMS_MAX];
    __shared__ int   sSlot[NMS_MAX];

    int g   = blockIdx.x;            // g = b*2 + (label-1)
    int tid = threadIdx.x;
    int V   = cnt[g];
    float*        gsc  = sc_ws + g*NCAND;
    const float4* obox = ob_ws + g*NCAND;
    const int*    nn   = n_ws  + g*NCAND;

    // load candidates into registers (coalesced: slot = k*512 + tid)
    float  sc_r[RSLOTS];
    float4 bx_r[RSLOTS];
    int    n_r[RSLOTS];
    #pragma unroll
    for (int k = 0; k < RSLOTS; ++k) {
        int i = k*NMS_THREADS + tid;
        if (i < V) { sc_r[k] = gsc[i]; bx_r[k] = obox[i]; n_r[k] = nn[i]; }
        else       { sc_r[k] = 0.f; bx_r[k] = make_float4(0.f,0.f,0.f,0.f); n_r[k] = 0; }
    }

    float4 prev = make_float4(-2.f, -2.f, -1.f, -1.f);   // dummy: IoU vs anything = 0
    int wid = tid >> 6, lane = tid & 63;
    int K = 0;

    for (int it = 0; it < NMS_MAX; ++it) {
        int p = it & 1;
        float a1 = (prev.z - prev.x) * (prev.w - prev.y);
        unsigned long long best = 0ull; int bslot = -1;

        #pragma unroll
        for (int k = 0; k < RSLOTS; ++k) {
            if (k*NMS_THREADS < V) {             // uniform: skip fully-empty tail slots
                float s = sc_r[k];
                if (s > 0.f) {
                    float4 bx = bx_r[k];
                    float ltx = fmaxf(prev.x, bx.x), lty = fmaxf(prev.y, bx.y);
                    float rbx = fminf(prev.z, bx.z), rby = fminf(prev.w, bx.w);
                    float ww = fmaxf(rbx - ltx, 0.f), hh = fmaxf(rby - lty, 0.f);
                    float inter = ww * hh;
                    float a2 = (bx.z - bx.x) * (bx.w - bx.y);
                    float iou = inter / (a1 + a2 - inter);   // exact div, matches reference
                    if (iou > NMS_TH) {
                        sc_r[k] = 0.f;                       // suppressed (also self-suppress, IoU==1)
                    } else {
                        unsigned long long key =
                            ((unsigned long long)__float_as_uint(s) << 32) | (unsigned)(~n_r[k]);
                        if (key > best) { best = key; bslot = k*NMS_THREADS + tid; }
                    }
                }
            }
        }
        // global tail for V > REGCAP (normally zero iterations)
        for (int i = REGCAP + tid; i < V; i += NMS_THREADS) {
            float s = gsc[i];
            if (s > 0.f) {
                float4 bx = obox[i];
                float ltx = fmaxf(prev.x, bx.x), lty = fmaxf(prev.y, bx.y);
                float rbx = fminf(prev.z, bx.z), rby = fminf(prev.w, bx.w);
                float ww = fmaxf(rbx - ltx, 0.f), hh = fmaxf(rby - lty, 0.f);
                float inter = ww * hh;
                float a2 = (bx.z - bx.x) * (bx.w - bx.y);
                float iou = inter / (a1 + a2 - inter);
                if (iou > NMS_TH) {
                    gsc[i] = 0.f;
                } else {
                    unsigned long long key =
                        ((unsigned long long)__float_as_uint(s) << 32) | (unsigned)(~nn[i]);
                    if (key > best) { best = key; bslot = i; }
                }
            }
        }

        // warp-level max of (key, slot)
        #pragma unroll
        for (int off = 32; off > 0; off >>= 1) {
            unsigned long long ok_ = __shfl_down(best, off);
            int os = __shfl_down(bslot, off);
            if (ok_ > best) { best = ok_; bslot = os; }
        }
        if (lane == 0) { warpKey[p][wid] = best; warpSlot[p][wid] = bslot; }
        __syncthreads();                          // the ONE barrier per iteration

        // every warp redundantly reduces the NW warp maxima (no second barrier needed)
        unsigned long long rk = (lane < NW) ? warpKey[p][lane] : 0ull;
        int rs = (lane < NW) ? warpSlot[p][lane] : -1;
        #pragma unroll
        for (int off = 4; off > 0; off >>= 1) {
            unsigned long long ok_ = __shfl_down(rk, off);
            int os = __shfl_down(rs, off);
            if (ok_ > rk) { rk = ok_; rs = os; }
        }
        rk = __shfl(rk, 0);
        rs = __shfl(rs, 0);

        if (!(rk >> 32)) break;                   // no live candidate anywhere -> done (uniform)

        if (tid == 0) {                           // record survivor in LDS (global flush later)
            sS[K]    = __uint_as_float((unsigned)(rk >> 32));
            sN[K]    = (int)(~(unsigned)rk);
            sSlot[K] = rs;
        }
        prev = obox[rs];                          // uniform-address broadcast load (1 line)
        ++K;
    }

    __syncthreads();
    for (int j = tid; j < K; j += NMS_THREADS) {
        survS[g*NMS_MAX + j] = sS[j];
        survN[g*NMS_MAX + j] = sN[j];
        survB[g*NMS_MAX + j] = rb_ws[g*NCAND + sSlot[j]];
    }
    if (tid == 0) Kout[g] = K;
}

// -------- Phase C: merge per-label survivor lists (640 cap), label-2 first, write out --------
__global__ __launch_bounds__(256) void write_out(
    const int* __restrict__ Kout, const float* __restrict__ survS,
    const int* __restrict__ survN, const float4* __restrict__ survB,
    float* __restrict__ out)
{
    int b = blockIdx.x, tid = threadIdx.x;
    __shared__ int t1s, t2s;
    int g1 = b*2 + 0, g2 = b*2 + 1;
    if (tid == 0) {
        int K1 = Kout[g1], K2 = Kout[g2];
        int take1 = K1, take2 = K2;
        if (K1 + K2 > NMS_MAX) {
            // global selection order = score-desc merge; tie by flat idx (n1 <= n2 => label-1 first)
            const float* s1 = survS + g1*NMS_MAX;
            const float* s2 = survS + g2*NMS_MAX;
            const int*   n1 = survN + g1*NMS_MAX;
            const int*   n2 = survN + g2*NMS_MAX;
            int i1 = 0, i2 = 0;
            for (int k = 0; k < NMS_MAX; ++k) {
                bool p1;
                if (i1 >= K1)      p1 = false;
                else if (i2 >= K2) p1 = true;
                else {
                    float a = s1[i1], c = s2[i2];
                    p1 = (a > c) || (a == c && n1[i1] <= n2[i2]);
                }
                if (p1) ++i1; else ++i2;
            }
            take1 = i1; take2 = i2;
        }
        t1s = take1; t2s = take2;
    }
    __syncthreads();
    int take1 = t1s, take2 = t2s;

    float* ob = out + b*DETS*4;
    float* os = out + B_IMG*DETS*4 + b*DETS;
    float* ol = out + B_IMG*DETS*5 + b*DETS;
    for (int p = tid; p < DETS; p += 256) {
        float4 bx = make_float4(0.f, 0.f, 0.f, 0.f);
        float sv = 0.f, lv = 0.f;
        if (p < take2) {
            int idx = g2*NMS_MAX + p;
            bx = survB[idx]; sv = survS[idx]; lv = 2.f;
        } else if (p - take2 < take1) {
            int idx = g1*NMS_MAX + (p - take2);
            bx = survB[idx]; sv = survS[idx]; lv = 1.f;
        }
        reinterpret_cast<float4*>(ob)[p] = bx;
        os[p] = sv;
        ol[p] = lv;
    }
}

extern "C" void kernel_launch(void* const* d_in, const int* in_sizes, int n_in,
                              void* d_out, int out_size, void* d_ws, size_t ws_size,
                              hipStream_t stream)
{
    const float* logits = (const float*)d_in[0];
    const float* rel    = (const float*)d_in[1];
    const float* props  = (const float*)d_in[2];
    const int*   imgsz  = (const int*)d_in[3];
    float* out = (float*)d_out;
    char*  ws  = (char*)d_ws;

    // workspace layout (~10.75 MB total)
    int*    cnt   = (int*)ws;                                   // 16 ints
    int*    Kout  = (int*)(ws + 64);                            // 16 ints
    float*  survS = (float*)(ws + 4096);                        // 16*640 f32
    int*    survN = (int*)(ws + 4096 + 40960);                  // 16*640 i32
    float4* survB = (float4*)(ws + 4096 + 81920);               // 16*640 f32x4
    float*  sc_ws = (float*)(ws + 262144);                      // 16*16384 f32 (1 MB)
    int*    n_ws  = (int*)(ws + 262144 + 1048576);              // 1 MB
    float4* ob_ws = (float4*)(ws + 262144 + 2097152);           // 4 MB (offset boxes)
    float4* rb_ws = (float4*)(ws + 262144 + 2097152 + 4194304); // 4 MB (raw boxes)

    hipMemsetAsync(cnt, 0, 64, stream);
    decode_compact<<<dim3(512), dim3(256), 0, stream>>>(logits, rel, props, imgsz,
                                                        cnt, sc_ws, n_ws, ob_ws, rb_ws);
    nms_greedy<<<dim3(16), dim3(NMS_THREADS), 0, stream>>>(sc_ws, n_ws, ob_ws, rb_ws,
                                                           cnt, Kout, survS, survN, survB);
    write_out<<<dim3(8), dim3(256), 0, stream>>>(Kout, survS, survN, survB, out);
}